// Round 5
// baseline (223.084 us; speedup 1.0000x reference)
//
#include <hip/hip_runtime.h>

#define B_    4
#define C_    192
#define N_    8192
#define K_    16
#define O_    192
#define TWOC_ 384

typedef __attribute__((ext_vector_type(8))) short short8;
typedef __attribute__((ext_vector_type(4))) short short4v;
typedef __attribute__((ext_vector_type(2))) unsigned int uint2v;
typedef __attribute__((ext_vector_type(4))) float floatx4;

static __device__ __forceinline__ float bf_lo(unsigned int u) {
    union { unsigned int i; float f; } v; v.i = u << 16; return v.f;
}
static __device__ __forceinline__ float bf_hi(unsigned int u) {
    union { unsigned int i; float f; } v; v.i = u & 0xffff0000u; return v.f;
}
static __device__ __forceinline__ unsigned short f2bf(float f) {
    union { float f; unsigned int i; } v; v.f = f;
    unsigned int x = v.i;
    return (unsigned short)((x + 0x7FFFu + ((x >> 16) & 1u)) >> 16);
}

// ---------------- K0a: W fp32 -> bf16 ----------------
__global__ __launch_bounds__(256) void k_convert_w(const float* __restrict__ W,
                                                   unsigned short* __restrict__ Wb) {
    int i = blockIdx.x * 256 + threadIdx.x;
    if (i < O_ * TWOC_) Wb[i] = f2bf(W[i]);
}

// ---------------- K0b: transpose x[B,C,N] fp32 -> xt[B,N,192] bf16 ----------------
__global__ __launch_bounds__(256) void k_transpose(const float* __restrict__ x,
                                                   unsigned short* __restrict__ xt) {
    __shared__ float tile[32][33];
    int bid  = blockIdx.x;               // 6144 blocks
    int xcd  = bid & 7;
    int b    = xcd >> 1;
    int half = xcd & 1;
    int slot = bid >> 3;                 // 0..767
    int ct   = slot >> 7;                // 0..5
    int nt   = half * 128 + (slot & 127);
    int c0 = ct * 32, n0 = nt * 32;
    int tid = threadIdx.x;

    int cc  = tid >> 3;
    int nn4 = (tid & 7) * 4;
    const float* xp = x + ((size_t)b * C_ + c0 + cc) * N_ + n0 + nn4;
    float4 v = *(const float4*)xp;
    tile[nn4 + 0][cc] = v.x;
    tile[nn4 + 1][cc] = v.y;
    tile[nn4 + 2][cc] = v.z;
    tile[nn4 + 3][cc] = v.w;
    __syncthreads();

#pragma unroll
    for (int i = 0; i < 2; i++) {
        int id  = i * 256 + tid;
        int row = id >> 4;
        int ch2 = id & 15;
        float a = tile[row][ch2 * 2];
        float c = tile[row][ch2 * 2 + 1];
        unsigned int pack = (unsigned int)f2bf(a) | ((unsigned int)f2bf(c) << 16);
        *(unsigned int*)(xt + ((size_t)b * N_ + n0 + row) * C_ + c0 + ch2 * 2) = pack;
    }
}

// ---------------- K1: standalone max-rel gather, 32 waves/CU ----------------
// Block = 16 nodes, 4 waves; each wave handles 4 nodes (lane groups of 16),
// depth-2 triple-buffered prefetch over k. LDS ~2.3 KiB -> 8 blocks/CU.
__global__ __launch_bounds__(256, 8) void k_gather(const unsigned short* __restrict__ xt,
                                                   const int* __restrict__ eidx,
                                                   unsigned short* __restrict__ rel) {
    __shared__ int sidx[16][36];         // 2.25 KiB, rows 16B-aligned

    int bid  = blockIdx.x;               // 2048 blocks
    int xcd  = bid & 7;
    int b    = xcd >> 1;
    int slot = bid >> 3;                 // 0..255
    int n0   = ((xcd & 1) * 256 + slot) * 16;

    int tid  = threadIdx.x;
    int wave = tid >> 6;
    int lane = tid & 63;

    // edge indices: sidx[node][0..15]=j (e0), [16..31]=i (e1). 256 loads each, coalesced.
    {
        const int* e0 = eidx + ((size_t)b * N_ + n0) * K_;
        const int* e1 = e0 + (size_t)B_ * N_ * K_;
        int node = tid >> 4, k = tid & 15;
        sidx[node][k]      = e0[tid];
        sidx[node][16 + k] = e1[tid];
    }
    __syncthreads();

    int g  = lane >> 4;
    int l4 = lane & 15;
    int node = wave * 4 + g;             // local node 0..15
    const unsigned short* xbase = xt + (size_t)b * N_ * C_;

#define GLD(BUF, JN, IN)                                                    \
    {                                                                       \
        const unsigned short* pj = xbase + (size_t)(JN) * C_ + l4 * 4;      \
        const unsigned short* pi = xbase + (size_t)(IN) * C_ + l4 * 4;      \
        bj[BUF][0] = *(const uint2v*)(pj);                                  \
        bi[BUF][0] = *(const uint2v*)(pi);                                  \
        bj[BUF][1] = *(const uint2v*)(pj + 64);                             \
        bi[BUF][1] = *(const uint2v*)(pi + 64);                             \
        bj[BUF][2] = *(const uint2v*)(pj + 128);                            \
        bi[BUF][2] = *(const uint2v*)(pi + 128);                            \
    }

    uint2v bj[3][3], bi[3][3];
    GLD(0, sidx[node][0], sidx[node][16]);
    GLD(1, sidx[node][1], sidx[node][17]);

    float m[3][4];
#pragma unroll
    for (int t = 0; t < 3; t++)
#pragma unroll
        for (int c = 0; c < 4; c++) m[t][c] = -INFINITY;

#pragma unroll
    for (int k = 0; k < K_; k++) {
        int cb = k % 3;
        if (k + 2 < K_) {
            int pb = (k + 2) % 3;
            GLD(pb, sidx[node][k + 2], sidx[node][16 + k + 2]);
        }
#pragma unroll
        for (int t = 0; t < 3; t++) {
            uint2v vj = bj[cb][t], vi = bi[cb][t];
            m[t][0] = fmaxf(m[t][0], bf_lo(vj.x) - bf_lo(vi.x));
            m[t][1] = fmaxf(m[t][1], bf_hi(vj.x) - bf_hi(vi.x));
            m[t][2] = fmaxf(m[t][2], bf_lo(vj.y) - bf_lo(vi.y));
            m[t][3] = fmaxf(m[t][3], bf_hi(vj.y) - bf_hi(vi.y));
        }
    }
#undef GLD

    unsigned short* w = rel + ((size_t)b * N_ + n0 + node) * C_;
#pragma unroll
    for (int t = 0; t < 3; t++) {
        short4v s;
        s.x = (short)f2bf(m[t][0]);
        s.y = (short)f2bf(m[t][1]);
        s.z = (short)f2bf(m[t][2]);
        s.w = (short)f2bf(m[t][3]);
        *(short4v*)(w + t * 64 + l4 * 4) = s;
    }
}

// ---------------- K2: out = ReLU(W1 . xs + W2 . rel + b), MFMA, 64x64 tiles ----------------
// One wave per 64o x 64n tile; A = W rows (K-contig), B = xt/rel rows (K-contig).
__global__ __launch_bounds__(64) void k_gemm(const unsigned short* __restrict__ Wb,
                                             const unsigned short* __restrict__ xt,
                                             const unsigned short* __restrict__ rel,
                                             const float* __restrict__ bias,
                                             float* __restrict__ out) {
    int bid  = blockIdx.x;               // 1536 blocks
    int xcd  = bid & 7;
    int b    = xcd >> 1;
    int rest = bid >> 3;                 // 0..191
    int ob   = rest / 64;                // 0..2
    int ns   = rest % 64;
    int n0   = ((xcd & 1) * 64 + ns) * 64;

    int lane = threadIdx.x;
    int m16  = lane & 15;
    int quad = lane >> 4;

    const unsigned short* wbase = Wb + (size_t)(ob * 64 + m16) * TWOC_ + quad * 8;
    const unsigned short* xrow  = xt  + ((size_t)b * N_ + n0 + m16) * C_ + quad * 8;
    const unsigned short* rrow  = rel + ((size_t)b * N_ + n0 + m16) * C_ + quad * 8;

    floatx4 acc[4][4];
#pragma unroll
    for (int i = 0; i < 4; i++)
#pragma unroll
        for (int j = 0; j < 4; j++) acc[i][j] = (floatx4){0.f, 0.f, 0.f, 0.f};

#pragma unroll
    for (int kt = 0; kt < 12; kt++) {
        const unsigned short* ybase = (kt < 6) ? xrow : rrow;
        int ko = (kt < 6) ? kt * 32 : (kt - 6) * 32;
        short8 af[4], yf[4];
#pragma unroll
        for (int t = 0; t < 4; t++)
            af[t] = *(const short8*)(wbase + (size_t)(t * 16) * TWOC_ + kt * 32);
#pragma unroll
        for (int t = 0; t < 4; t++)
            yf[t] = *(const short8*)(ybase + (size_t)(t * 16) * C_ + ko);
#pragma unroll
        for (int i = 0; i < 4; i++)
#pragma unroll
            for (int j = 0; j < 4; j++)
                acc[i][j] = __builtin_amdgcn_mfma_f32_16x16x32_bf16(af[i], yf[j], acc[i][j], 0, 0, 0);
    }

#pragma unroll
    for (int i = 0; i < 4; i++) {
#pragma unroll
        for (int r = 0; r < 4; r++) {
            int o = ob * 64 + i * 16 + quad * 4 + r;
            float bv = bias[o];
#pragma unroll
            for (int j = 0; j < 4; j++) {
                int n = n0 + j * 16 + m16;
                out[((size_t)b * O_ + o) * N_ + n] = fmaxf(acc[i][j][r] + bv, 0.f);
            }
        }
    }
}

extern "C" void kernel_launch(void* const* d_in, const int* in_sizes, int n_in,
                              void* d_out, int out_size, void* d_ws, size_t ws_size,
                              hipStream_t stream) {
    const float* x    = (const float*)d_in[0];
    const int*   eidx = (const int*)d_in[2];
    const float* W    = (const float*)d_in[3];
    const float* bias = (const float*)d_in[4];
    float*       out  = (float*)d_out;

    unsigned short* Wb  = (unsigned short*)d_ws;                      // 147456 B
    unsigned short* xt  = (unsigned short*)((char*)d_ws + 147456);    // 12.58 MB
    unsigned short* rel = (unsigned short*)((char*)d_ws + 147456 + (size_t)B_ * N_ * C_ * 2);

    k_convert_w<<<dim3(288), dim3(256), 0, stream>>>(W, Wb);
    k_transpose<<<dim3(6144), dim3(256), 0, stream>>>(x, xt);
    k_gather<<<dim3(2048), dim3(256), 0, stream>>>(xt, eidx, rel);
    k_gemm<<<dim3(1536), dim3(64), 0, stream>>>(Wb, xt, rel, bias, out);
}